// Round 2
// baseline (562.592 us; speedup 1.0000x reference)
//
#include <hip/hip_runtime.h>

#define NN 50000     // nodes
#define NE 200000    // edges
#define DF 364       // feature dim (= 91 float4)
#define DOUT 150     // output dim
#define NP 8192      // pairs
#define NEG_SLOPE 0.01f

// ---------------- CSR build ----------------

__global__ void hist_kernel(const int* __restrict__ dst, int* __restrict__ deg, int n) {
    int t = blockIdx.x * blockDim.x + threadIdx.x;
    if (t < n) atomicAdd(&deg[dst[t]], 1);
}

// per-block exclusive scan of deg -> rowptr (block-local), block totals -> bsum
__global__ __launch_bounds__(1024) void scan_block(const int* __restrict__ deg,
                                                   int* __restrict__ rowptr,
                                                   int* __restrict__ bsum, int n) {
    __shared__ int lds[1024];
    int b = blockIdx.x, t = threadIdx.x;
    int i = b * 1024 + t;
    int v = (i < n) ? deg[i] : 0;
    lds[t] = v;
    __syncthreads();
    for (int off = 1; off < 1024; off <<= 1) {
        int x = (t >= off) ? lds[t - off] : 0;
        __syncthreads();
        lds[t] += x;
        __syncthreads();
    }
    if (i < n) rowptr[i] = lds[t] - v;          // block-local exclusive
    if (t == 1023) bsum[b] = lds[1023];         // block total
}

// single-wave exclusive scan of <=64 block sums (in place)
__global__ void scan_small(int* __restrict__ bsum, int nb) {
    int t = threadIdx.x;
    int orig = (t < nb) ? bsum[t] : 0;
    int v = orig;
#pragma unroll
    for (int off = 1; off < 64; off <<= 1) {
        int u = __shfl_up(v, off, 64);
        if (t >= off) v += u;
    }
    if (t < nb) bsum[t] = v - orig;             // exclusive
}

// rowptr[i] += bsum[block]; also initializes pos[i] (insertion cursor)
__global__ __launch_bounds__(1024) void add_off(int* __restrict__ rowptr,
                                                const int* __restrict__ bsum,
                                                int* __restrict__ pos, int n) {
    int i = blockIdx.x * 1024 + threadIdx.x;
    if (i < n) {
        int v = rowptr[i] + bsum[blockIdx.x];
        rowptr[i] = v;
        pos[i] = v;
    }
}

__global__ void fill_kernel(const int* __restrict__ src, const int* __restrict__ dst,
                            int* __restrict__ pos, int* __restrict__ esrc, int n) {
    int t = blockIdx.x * blockDim.x + threadIdx.x;
    if (t < n) {
        int j = atomicAdd(&pos[dst[t]], 1);
        esrc[j] = src[t];
    }
}

// ---------------- aggregation: out[row] = x[node] + sum_{in-edges} x[src] ----------------
// one wave per output row; lane i owns float4 #i (cols 4i..4i+3) and, for i<27,
// float4 #(64+i) (cols 256+4i..259+4i). 91 float4 = 364 cols.

__device__ __forceinline__ void f4add(float4& a, const float4 b) {
    a.x += b.x; a.y += b.y; a.z += b.z; a.w += b.w;
}

__global__ __launch_bounds__(256) void agg_kernel(
    const float* __restrict__ x, const int* __restrict__ rowptr,
    const int* __restrict__ deg, const int* __restrict__ esrc,
    const int* __restrict__ v1, const int* __restrict__ v2,
    float* __restrict__ out, int nrows) {
    int wid = (blockIdx.x * 256 + threadIdx.x) >> 6;
    if (wid >= nrows) return;
    int lane = threadIdx.x & 63;
    int node = wid;
    if (v1) node = (wid < NP) ? v1[wid] : v2[wid - NP];
    int start = rowptr[node];
    int d = deg[node];
    bool hi = (lane < DF / 4 - 64);  // lane < 27

    const float4* xr = reinterpret_cast<const float4*>(x + (size_t)node * DF);
    float4 a0 = xr[lane];
    float4 a1 = make_float4(0.f, 0.f, 0.f, 0.f);
    if (hi) a1 = xr[64 + lane];

    int j = 0;
    for (; j + 1 < d; j += 2) {  // 2-edge unroll: more outstanding loads
        int s0 = esrc[start + j], s1 = esrc[start + j + 1];
        const float4* r0 = reinterpret_cast<const float4*>(x + (size_t)s0 * DF);
        const float4* r1 = reinterpret_cast<const float4*>(x + (size_t)s1 * DF);
        float4 b0 = r0[lane], b1 = r1[lane];
        f4add(a0, b0);
        f4add(a0, b1);
        if (hi) {
            float4 c0 = r0[64 + lane], c1 = r1[64 + lane];
            f4add(a1, c0);
            f4add(a1, c1);
        }
    }
    if (j < d) {
        int s0 = esrc[start + j];
        const float4* r0 = reinterpret_cast<const float4*>(x + (size_t)s0 * DF);
        f4add(a0, r0[lane]);
        if (hi) f4add(a1, r0[64 + lane]);
    }

    float4* orow = reinterpret_cast<float4*>(out + (size_t)wid * DF);
    orow[lane] = a0;
    if (hi) orow[64 + lane] = a1;
}

// ---------------- GEMM: C[M,N] = lrelu(A[M,K] @ B[K,N] + bias) ----------------
// 64x64 tile, BK=16, 256 threads, 4x4 per thread, zero-padded K tail.

#define BM 64
#define BN 64
#define BK 16

__global__ __launch_bounds__(256) void gemm_bias_lrelu(
    const float* __restrict__ A, const float* __restrict__ B,
    const float* __restrict__ bias, float* __restrict__ C,
    int M, int N, int K) {
    __shared__ float As[BK][BM + 4];  // stride 68 floats (272 B, 16B-aligned rows)
    __shared__ float Bs[BK][BN];

    int tid = threadIdx.x;
    int tx = tid & 15, ty = tid >> 4;
    int blockM = blockIdx.x * BM;
    int blockN = blockIdx.y * BN;

    float c[4][4] = {};

    for (int kk = 0; kk < K; kk += BK) {
        // A tile: thread -> (m = tid/4, k4 = tid%4), float4 along k. K%4==0 so the
        // guard covers all 4 elements; OOB -> zero-fill.
        {
            int m = tid >> 2, k4 = tid & 3;
            int row = blockM + m;
            int kcol = kk + k4 * 4;
            float4 av = make_float4(0.f, 0.f, 0.f, 0.f);
            if (row < M && kcol < K)
                av = *reinterpret_cast<const float4*>(A + (size_t)row * K + kcol);
            As[k4 * 4 + 0][m] = av.x;
            As[k4 * 4 + 1][m] = av.y;
            As[k4 * 4 + 2][m] = av.z;
            As[k4 * 4 + 3][m] = av.w;
        }
        // B tile: thread -> (k = tid/16, n4 = tid%16); row guard zero-fills K tail.
        {
            int k = tid >> 4, n4 = tid & 15;
            int row = kk + k;
            int coln = blockN + n4 * 4;
            float4 bv = make_float4(0.f, 0.f, 0.f, 0.f);
            if (row < K) {
                const float* bp = B + (size_t)row * N + coln;
                if ((N & 3) == 0) {
                    if (coln < N) bv = *reinterpret_cast<const float4*>(bp);
                } else {  // N=150: scalar guarded loads (avoids misaligned float4)
                    if (coln + 0 < N) bv.x = bp[0];
                    if (coln + 1 < N) bv.y = bp[1];
                    if (coln + 2 < N) bv.z = bp[2];
                    if (coln + 3 < N) bv.w = bp[3];
                }
            }
            *reinterpret_cast<float4*>(&Bs[k][n4 * 4]) = bv;
        }
        __syncthreads();
#pragma unroll
        for (int k = 0; k < BK; ++k) {
            float4 a4 = *reinterpret_cast<const float4*>(&As[k][ty * 4]);
            float4 b4 = *reinterpret_cast<const float4*>(&Bs[k][tx * 4]);
            float av[4] = {a4.x, a4.y, a4.z, a4.w};
            float bvv[4] = {b4.x, b4.y, b4.z, b4.w};
#pragma unroll
            for (int i = 0; i < 4; ++i)
#pragma unroll
                for (int j = 0; j < 4; ++j) c[i][j] += av[i] * bvv[j];
        }
        __syncthreads();
    }

#pragma unroll
    for (int i = 0; i < 4; ++i) {
        int r = blockM + ty * 4 + i;
        if (r >= M) continue;
#pragma unroll
        for (int j = 0; j < 4; ++j) {
            int col = blockN + tx * 4 + j;
            if (col >= N) continue;
            float v = c[i][j] + bias[col];
            v = (v >= 0.f) ? v : NEG_SLOPE * v;
            C[(size_t)r * N + col] = v;
        }
    }
}

// ---------------- row L2 normalize (in place), one wave per row of 150 ----------------

__global__ __launch_bounds__(256) void norm_kernel(float* __restrict__ out, int nrows) {
    int wid = (blockIdx.x * 256 + threadIdx.x) >> 6;
    if (wid >= nrows) return;
    int lane = threadIdx.x & 63;
    float* row = out + (size_t)wid * DOUT;
    float a = row[lane];
    float b = row[lane + 64];  // lane+64 in [64,128) < 150 always
    float cc = (lane + 128 < DOUT) ? row[lane + 128] : 0.f;
    float s = a * a + b * b + cc * cc;
#pragma unroll
    for (int off = 32; off; off >>= 1) s += __shfl_xor(s, off, 64);
    float scale = 1.0f / fmaxf(sqrtf(s), 1e-12f);
    row[lane] = a * scale;
    row[lane + 64] = b * scale;
    if (lane + 128 < DOUT) row[lane + 128] = cc * scale;
}

// ---------------- launch ----------------

extern "C" void kernel_launch(void* const* d_in, const int* in_sizes, int n_in,
                              void* d_out, int out_size, void* d_ws, size_t ws_size,
                              hipStream_t stream) {
    const float* features = (const float*)d_in[0];
    const int* src = (const int*)d_in[1];
    const int* dst = (const int*)d_in[2];
    const int* v1 = (const int*)d_in[3];
    const int* v2 = (const int*)d_in[4];
    const float* W1 = (const float*)d_in[5];
    const float* b1 = (const float*)d_in[6];
    const float* W2 = (const float*)d_in[7];
    const float* b2 = (const float*)d_in[8];
    const float* W3 = (const float*)d_in[9];
    const float* b3 = (const float*)d_in[10];
    float* out = (float*)d_out;

    // workspace layout (~147 MB)
    float* agg = (float*)d_ws;                       // 50000*364 f32
    float* h1 = agg + (size_t)NN * DF;               // 50000*364 f32
    int* deg = (int*)(h1 + (size_t)NN * DF);         // 50000
    int* rowptr = deg + NN;                          // 50000
    int* pos = rowptr + NN;                          // 50000
    int* esrc = pos + NN;                            // 200000
    int* bsum = esrc + NE;                           // 64

    const int NSB = (NN + 1023) / 1024;  // 49 scan blocks

    // CSR build (once per call, reused by both layers)
    hipMemsetAsync(deg, 0, NN * sizeof(int), stream);
    hist_kernel<<<(NE + 255) / 256, 256, 0, stream>>>(dst, deg, NE);
    scan_block<<<NSB, 1024, 0, stream>>>(deg, rowptr, bsum, NN);
    scan_small<<<1, 64, 0, stream>>>(bsum, NSB);
    add_off<<<NSB, 1024, 0, stream>>>(rowptr, bsum, pos, NN);
    fill_kernel<<<(NE + 255) / 256, 256, 0, stream>>>(src, dst, pos, esrc, NE);

    // layer 1: all 50000 nodes
    agg_kernel<<<(NN * 64 + 255) / 256, 256, 0, stream>>>(features, rowptr, deg, esrc,
                                                          nullptr, nullptr, agg, NN);
    dim3 g1((NN + BM - 1) / BM, (DF + BN - 1) / BN);
    gemm_bias_lrelu<<<g1, 256, 0, stream>>>(agg, W1, b1, h1, NN, DF, DF);

    // layer 2: only the 16384 rows that feed the output
    const int NR = 2 * NP;
    agg_kernel<<<(NR * 64 + 255) / 256, 256, 0, stream>>>(h1, rowptr, deg, esrc,
                                                          v1, v2, agg, NR);
    dim3 g2((NR + BM - 1) / BM, (DF + BN - 1) / BN);
    gemm_bias_lrelu<<<g2, 256, 0, stream>>>(agg, W2, b2, h1, NR, DF, DF);

    // final projection + lrelu into d_out, then in-place L2 normalize
    dim3 g3((NR + BM - 1) / BM, (DOUT + BN - 1) / BN);
    gemm_bias_lrelu<<<g3, 256, 0, stream>>>(h1, W3, b3, out, NR, DOUT, DF);
    norm_kernel<<<(NR * 64 + 255) / 256, 256, 0, stream>>>(out, NR);
}

// Round 5
// 395.212 us; speedup vs baseline: 1.4235x; 1.4235x over previous
//
#include <hip/hip_runtime.h>

#define NN 50000     // nodes
#define NE 200000    // edges
#define DF 364       // feature dim
#define KP 384       // padded K (12 x 32)
#define DOUT 150     // output dim
#define NP 8192      // pairs
#define NEG_SLOPE 0.01f

typedef float f32x4 __attribute__((ext_vector_type(4)));
typedef short bf16x8 __attribute__((ext_vector_type(8)));

__device__ __forceinline__ unsigned short f2bf(float x) {
    unsigned u = __float_as_uint(x);
    u += 0x7FFF + ((u >> 16) & 1);  // RN-even; inputs finite
    return (unsigned short)(u >> 16);
}
__device__ __forceinline__ float bf2f(unsigned short h) {
    return __uint_as_float(((unsigned)h) << 16);
}

__device__ __forceinline__ void mfma16(f32x4& d, bf16x8 a, bf16x8 b) {
    d = __builtin_amdgcn_mfma_f32_16x16x32_bf16(a, b, d, 0, 0, 0);
}

// ---------------- CSR build ----------------

__global__ void hist_kernel(const int* __restrict__ dst, int* __restrict__ deg, int n) {
    int t = blockIdx.x * blockDim.x + threadIdx.x;
    if (t < n) atomicAdd(&deg[dst[t]], 1);
}

__global__ __launch_bounds__(1024) void scan_block(const int* __restrict__ deg,
                                                   int* __restrict__ rowptr,
                                                   int* __restrict__ bsum, int n) {
    __shared__ int lds[1024];
    int b = blockIdx.x, t = threadIdx.x;
    int i = b * 1024 + t;
    int v = (i < n) ? deg[i] : 0;
    lds[t] = v;
    __syncthreads();
    for (int off = 1; off < 1024; off <<= 1) {
        int x = (t >= off) ? lds[t - off] : 0;
        __syncthreads();
        lds[t] += x;
        __syncthreads();
    }
    if (i < n) rowptr[i] = lds[t] - v;
    if (t == 1023) bsum[b] = lds[1023];
}

__global__ void scan_small(int* __restrict__ bsum, int nb) {
    int t = threadIdx.x;
    int orig = (t < nb) ? bsum[t] : 0;
    int v = orig;
#pragma unroll
    for (int off = 1; off < 64; off <<= 1) {
        int u = __shfl_up(v, off, 64);
        if (t >= off) v += u;
    }
    if (t < nb) bsum[t] = v - orig;
}

__global__ __launch_bounds__(1024) void add_off(int* __restrict__ rowptr,
                                                const int* __restrict__ bsum,
                                                int* __restrict__ pos, int n) {
    int i = blockIdx.x * 1024 + threadIdx.x;
    if (i < n) {
        int v = rowptr[i] + bsum[blockIdx.x];
        rowptr[i] = v;
        pos[i] = v;
    }
}

__global__ void fill_kernel(const int* __restrict__ src, const int* __restrict__ dst,
                            int* __restrict__ pos, int* __restrict__ esrc, int n) {
    int t = blockIdx.x * blockDim.x + threadIdx.x;
    if (t < n) {
        int j = atomicAdd(&pos[dst[t]], 1);
        esrc[j] = src[t];
    }
}

// ---------------- split-plane helpers ----------------

__device__ __forceinline__ void store4(ushort* oh, ushort* ol, size_t off, float4 v) {
    ushort4 h, l;
    h.x = f2bf(v.x); l.x = f2bf(v.x - bf2f(h.x));
    h.y = f2bf(v.y); l.y = f2bf(v.y - bf2f(h.y));
    h.z = f2bf(v.z); l.z = f2bf(v.z - bf2f(h.z));
    h.w = f2bf(v.w); l.w = f2bf(v.w - bf2f(h.w));
    *(ushort4*)&oh[off] = h;
    *(ushort4*)&ol[off] = l;
}

__device__ __forceinline__ float4 load4(const ushort* ih, const ushort* il, size_t off) {
    ushort4 h = *(const ushort4*)&ih[off];
    ushort4 l = *(const ushort4*)&il[off];
    return make_float4(bf2f(h.x) + bf2f(l.x), bf2f(h.y) + bf2f(l.y),
                       bf2f(h.z) + bf2f(l.z), bf2f(h.w) + bf2f(l.w));
}

__device__ __forceinline__ void f4add(float4& a, const float4 b) {
    a.x += b.x; a.y += b.y; a.z += b.z; a.w += b.w;
}

// ---------------- agg1: fp32 features -> split planes [NN pad][KP] ----------------

__global__ __launch_bounds__(256) void agg1_kernel(
    const float* __restrict__ x, const int* __restrict__ rowptr,
    const int* __restrict__ deg, const int* __restrict__ esrc,
    ushort* __restrict__ oh, ushort* __restrict__ ol, int nrows) {
    int wid = (blockIdx.x * 256 + threadIdx.x) >> 6;
    if (wid >= nrows) return;
    int lane = threadIdx.x & 63;
    int start = rowptr[wid];
    int d = deg[wid];
    bool hi2 = lane < 27;  // 91 float4 chunks: lane + (64+lane for lane<27)

    const float4* xr = reinterpret_cast<const float4*>(x + (size_t)wid * DF);
    float4 a0 = xr[lane];
    float4 a1 = hi2 ? xr[64 + lane] : make_float4(0.f, 0.f, 0.f, 0.f);

    int j = 0;
    for (; j + 1 < d; j += 2) {
        int s0 = esrc[start + j], s1 = esrc[start + j + 1];
        const float4* r0 = reinterpret_cast<const float4*>(x + (size_t)s0 * DF);
        const float4* r1 = reinterpret_cast<const float4*>(x + (size_t)s1 * DF);
        float4 b0 = r0[lane], b1 = r1[lane];
        f4add(a0, b0);
        f4add(a0, b1);
        if (hi2) {
            float4 c0 = r0[64 + lane], c1 = r1[64 + lane];
            f4add(a1, c0);
            f4add(a1, c1);
        }
    }
    if (j < d) {
        int s0 = esrc[start + j];
        const float4* r0 = reinterpret_cast<const float4*>(x + (size_t)s0 * DF);
        f4add(a0, r0[lane]);
        if (hi2) f4add(a1, r0[64 + lane]);
    }

    size_t rb = (size_t)wid * KP;
    store4(oh, ol, rb + 4 * lane, a0);
    if (lane < 32) {  // elems 256..383; lanes 27..31 zero-pad 364..383
        float4 v = hi2 ? a1 : make_float4(0.f, 0.f, 0.f, 0.f);
        store4(oh, ol, rb + 256 + 4 * lane, v);
    }
}

// ---------------- agg2: split planes -> split planes, gathered rows ----------------

__global__ __launch_bounds__(256) void agg2_kernel(
    const ushort* __restrict__ ih, const ushort* __restrict__ il,
    const int* __restrict__ rowptr, const int* __restrict__ deg,
    const int* __restrict__ esrc, const int* __restrict__ v1,
    const int* __restrict__ v2,
    ushort* __restrict__ oh, ushort* __restrict__ ol, int nrows) {
    int wid = (blockIdx.x * 256 + threadIdx.x) >> 6;
    if (wid >= nrows) return;
    int lane = threadIdx.x & 63;
    int node = (wid < NP) ? v1[wid] : v2[wid - NP];
    int start = rowptr[node];
    int d = deg[node];
    bool hi2 = lane < 27;

    size_t nb = (size_t)node * KP;
    float4 a0 = load4(ih, il, nb + 4 * lane);
    float4 a1 = hi2 ? load4(ih, il, nb + 256 + 4 * lane) : make_float4(0.f, 0.f, 0.f, 0.f);

    for (int j = 0; j < d; ++j) {
        int s = esrc[start + j];
        size_t sb = (size_t)s * KP;
        f4add(a0, load4(ih, il, sb + 4 * lane));
        if (hi2) f4add(a1, load4(ih, il, sb + 256 + 4 * lane));
    }

    size_t rb = (size_t)wid * KP;
    store4(oh, ol, rb + 4 * lane, a0);
    if (lane < 32) {
        float4 v = hi2 ? a1 : make_float4(0.f, 0.f, 0.f, 0.f);
        store4(oh, ol, rb + 256 + 4 * lane, v);
    }
}

// ---------------- weight prep: W[K][N] fp32 -> WT hi/lo planes [KP n][KP k] ----------------

__global__ void prep_w(const float* __restrict__ W, int K, int N,
                       ushort* __restrict__ th, ushort* __restrict__ tl) {
    int idx = blockIdx.x * 256 + threadIdx.x;
    if (idx >= KP * KP) return;
    int n = idx / KP;
    int k = idx - n * KP;
    float v = (k < K && n < N) ? W[(size_t)k * N + n] : 0.f;
    unsigned short h = f2bf(v);
    th[idx] = h;
    tl[idx] = f2bf(v - bf2f(h));
}

// ---------------- MFMA GEMM: C = lrelu(A @ WT^T + bias) ----------------
// A planes [Mpad][KP], WT planes [KP n][KP k]. 128x128 tile, 4 waves (2x2), each 64x64.
// Split-bf16: acc += ah*bh + ah*bl + al*bh  (fp32-grade accuracy).
// LDS tile per plane: [128 rows][32 k] bf16, linear (NO swizzle): rows are 64 B —
// fragment read (chunk=lane>>4, row=lane&15) gives bank = 16*(l&1)+4*(l>>4)+w,
// i.e. uniform 8 words/bank across all 32 banks = the 1024 B minimum. Conflict-free
// without any swizzle. Staged via global_load_lds w=16, linear dest + linear src.

__global__ __launch_bounds__(256, 2) void gemm_mfma(
    const ushort* __restrict__ Ahi, const ushort* __restrict__ Alo,
    const ushort* __restrict__ WTh, const ushort* __restrict__ WTl,
    const float* __restrict__ bias,
    ushort* __restrict__ Chi, ushort* __restrict__ Clo,
    float* __restrict__ Cf32, int M, int N) {
    __shared__ __align__(16) ushort lds[2][4][4096];  // 64 KB

    int tid = threadIdx.x;
    int lane = tid & 63;
    int wv = tid >> 6;           // wave 0..3; also = staged plane
    int wr = wv >> 1, wc = wv & 1;
    int brow = blockIdx.x * 128, bcol = blockIdx.y * 128;

    // staging source (per lane, LINEAR): dest byte = lane*16 -> row = lane>>2,
    // 16B-chunk-in-row = lane&3. Source address mirrors that exactly.
    int srow = lane >> 2;
    int skc = lane & 3;
    const ushort* gsrc;
    {
        size_t lo = (size_t)srow * KP + (size_t)skc * 8;
        if (wv == 0)      gsrc = Ahi + (size_t)brow * KP + lo;
        else if (wv == 1) gsrc = Alo + (size_t)brow * KP + lo;
        else if (wv == 2) gsrc = WTh + (size_t)bcol * KP + lo;
        else              gsrc = WTl + (size_t)bcol * KP + lo;
    }

#define STAGE(buf, t)                                                                   \
    do {                                                                                \
        const ushort* s_ = gsrc + (t) * 32;                                             \
        _Pragma("unroll") for (int i_ = 0; i_ < 8; ++i_) {                              \
            __builtin_amdgcn_global_load_lds(                                           \
                (const __attribute__((address_space(1))) unsigned int*)(s_ + (size_t)i_ * 16 * KP), \
                (__attribute__((address_space(3))) unsigned int*)(&lds[buf][wv][i_ * 512]), \
                16, 0, 0);                                                              \
        }                                                                               \
    } while (0)

    // fragment read (LINEAR): row = lane&15 (+16m +64wr/wc), k-chunk = lane>>4
    int koff = (lane >> 4) * 8;                 // ushort offset within 32-k row
    int a_off = (wr * 64 + (lane & 15)) * 32 + koff;
    int b_off = (wc * 64 + (lane & 15)) * 32 + koff;

    f32x4 acc[4][4];
#pragma unroll
    for (int m = 0; m < 4; ++m)
#pragma unroll
        for (int n = 0; n < 4; ++n) acc[m][n] = (f32x4){0.f, 0.f, 0.f, 0.f};

    const int NT = KP / 32;  // 12
    STAGE(0, 0);
    __syncthreads();

    for (int t = 0; t < NT; ++t) {
        int cur = t & 1;
        if (t + 1 < NT) STAGE(1 - cur, t + 1);
        const ushort* L = &lds[cur][0][0];
        bf16x8 ah[4], al[4], bh[4], bl[4];
#pragma unroll
        for (int m = 0; m < 4; ++m) {
            ah[m] = *(const bf16x8*)(L + 0 * 4096 + a_off + m * 512);
            al[m] = *(const bf16x8*)(L + 1 * 4096 + a_off + m * 512);
        }
#pragma unroll
        for (int n = 0; n < 4; ++n) {
            bh[n] = *(const bf16x8*)(L + 2 * 4096 + b_off + n * 512);
            bl[n] = *(const bf16x8*)(L + 3 * 4096 + b_off + n * 512);
        }
#pragma unroll
        for (int m = 0; m < 4; ++m)
#pragma unroll
            for (int n = 0; n < 4; ++n) {
                mfma16(acc[m][n], ah[m], bh[n]);
                mfma16(acc[m][n], ah[m], bl[n]);
                mfma16(acc[m][n], al[m], bh[n]);
            }
        __syncthreads();
    }
#undef STAGE

    // epilogue: C/D layout col=lane&15, row=(lane>>4)*4+reg  [m89-verified]
    int crow_l = (lane >> 4) * 4;
    int ccol_l = lane & 15;
#pragma unroll
    for (int n = 0; n < 4; ++n) {
        int col = bcol + wc * 64 + n * 16 + ccol_l;
        bool cok = (col < N);
        float bn = cok ? bias[col] : 0.f;
#pragma unroll
        for (int m = 0; m < 4; ++m) {
#pragma unroll
            for (int r = 0; r < 4; ++r) {
                int row = brow + wr * 64 + m * 16 + crow_l + r;
                if (row >= M) continue;
                float v = acc[m][n][r] + bn;
                v = (v >= 0.f) ? v : NEG_SLOPE * v;
                if (Cf32) {
                    if (cok) Cf32[(size_t)row * N + col] = v;
                } else {
                    unsigned short h = 0, l = 0;
                    if (cok) {
                        h = f2bf(v);
                        l = f2bf(v - bf2f(h));
                    }
                    // col<KP always (grid covers 0..383); zero-fill pad cols
                    Chi[(size_t)row * KP + col] = h;
                    Clo[(size_t)row * KP + col] = l;
                }
            }
        }
    }
}

// ---------------- row L2 normalize (in place) ----------------

__global__ __launch_bounds__(256) void norm_kernel(float* __restrict__ out, int nrows) {
    int wid = (blockIdx.x * 256 + threadIdx.x) >> 6;
    if (wid >= nrows) return;
    int lane = threadIdx.x & 63;
    float* row = out + (size_t)wid * DOUT;
    float a = row[lane];
    float b = row[lane + 64];
    float cc = (lane + 128 < DOUT) ? row[lane + 128] : 0.f;
    float s = a * a + b * b + cc * cc;
#pragma unroll
    for (int off = 32; off; off >>= 1) s += __shfl_xor(s, off, 64);
    float scale = 1.0f / fmaxf(sqrtf(s), 1e-12f);
    row[lane] = a * scale;
    row[lane + 64] = b * scale;
    if (lane + 128 < DOUT) row[lane + 128] = cc * scale;
}

// ---------------- launch ----------------

extern "C" void kernel_launch(void* const* d_in, const int* in_sizes, int n_in,
                              void* d_out, int out_size, void* d_ws, size_t ws_size,
                              hipStream_t stream) {
    const float* features = (const float*)d_in[0];
    const int* src = (const int*)d_in[1];
    const int* dst = (const int*)d_in[2];
    const int* v1 = (const int*)d_in[3];
    const int* v2 = (const int*)d_in[4];
    const float* W1 = (const float*)d_in[5];
    const float* b1 = (const float*)d_in[6];
    const float* W2 = (const float*)d_in[7];
    const float* b2 = (const float*)d_in[8];
    const float* W3 = (const float*)d_in[9];
    const float* b3 = (const float*)d_in[10];
    float* out = (float*)d_out;

    const int MPAD = 50048;                  // 391 * 128
    const size_t PLANE = (size_t)MPAD * KP;  // elems (ushort)
    const size_t WSZ = (size_t)KP * KP;

    char* p = (char*)d_ws;
    ushort* a1h = (ushort*)p; p += PLANE * 2;
    ushort* a1l = (ushort*)p; p += PLANE * 2;
    ushort* h1h = (ushort*)p; p += PLANE * 2;
    ushort* h1l = (ushort*)p; p += PLANE * 2;
    ushort* wt1h = (ushort*)p; p += WSZ * 2;
    ushort* wt1l = (ushort*)p; p += WSZ * 2;
    ushort* wt2h = (ushort*)p; p += WSZ * 2;
    ushort* wt2l = (ushort*)p; p += WSZ * 2;
    ushort* wt3h = (ushort*)p; p += WSZ * 2;
    ushort* wt3l = (ushort*)p; p += WSZ * 2;
    int* deg = (int*)p; p += NN * 4;
    int* rowptr = (int*)p; p += NN * 4;
    int* pos = (int*)p; p += NN * 4;
    int* esrc = (int*)p; p += NE * 4;
    int* bsum = (int*)p; p += 256;
    // reuse after consumers finish:
    ushort* a2h = a1h;  // layer-2 agg out (16384 rows) reuses a1
    ushort* a2l = a1l;
    ushort* h2h = h1h;  // layer-2 gemm out reuses h1
    ushort* h2l = h1l;

    const int NSB = (NN + 1023) / 1024;

    hipMemsetAsync(deg, 0, NN * sizeof(int), stream);
    hist_kernel<<<(NE + 255) / 256, 256, 0, stream>>>(dst, deg, NE);
    scan_block<<<NSB, 1024, 0, stream>>>(deg, rowptr, bsum, NN);
    scan_small<<<1, 64, 0, stream>>>(bsum, NSB);
    add_off<<<NSB, 1024, 0, stream>>>(rowptr, bsum, pos, NN);
    fill_kernel<<<(NE + 255) / 256, 256, 0, stream>>>(src, dst, pos, esrc, NE);

    prep_w<<<(KP * KP + 255) / 256, 256, 0, stream>>>(W1, DF, DF, wt1h, wt1l);
    prep_w<<<(KP * KP + 255) / 256, 256, 0, stream>>>(W2, DF, DF, wt2h, wt2l);
    prep_w<<<(KP * KP + 255) / 256, 256, 0, stream>>>(W3, DF, DOUT, wt3h, wt3l);

    // layer 1 (all nodes)
    agg1_kernel<<<(NN * 64 + 255) / 256, 256, 0, stream>>>(features, rowptr, deg, esrc,
                                                           a1h, a1l, NN);
    gemm_mfma<<<dim3(391, 3), 256, 0, stream>>>(a1h, a1l, wt1h, wt1l, b1,
                                                h1h, h1l, nullptr, NN, DF);

    // layer 2 (only the 16384 gathered rows)
    const int NR = 2 * NP;
    agg2_kernel<<<(NR * 64 + 255) / 256, 256, 0, stream>>>(h1h, h1l, rowptr, deg, esrc,
                                                           v1, v2, a2h, a2l, NR);
    gemm_mfma<<<dim3(128, 3), 256, 0, stream>>>(a2h, a2l, wt2h, wt2l, b2,
                                                h2h, h2l, nullptr, NR, DF);

    // projection -> d_out (fp32), then in-place normalize
    gemm_mfma<<<dim3(128, 2), 256, 0, stream>>>(h2h, h2l, wt3h, wt3l, b3,
                                                nullptr, nullptr, out, NR, DOUT);
    norm_kernel<<<(NR * 64 + 255) / 256, 256, 0, stream>>>(out, NR);
}